// Round 1
// baseline (92.754 us; speedup 1.0000x reference)
//
#include <hip/hip_runtime.h>

// ThinPlateSpline: out = K_query @ rbf_weights + P_query @ poly_coeffs
//   K_ij = r * ln(r),  r = ||u_i - c_j||,  guarded to 0 for r < 1e-10
//   P_i  = [1, u_i]  (d=3 -> m=4)
//
// Strategy: compute-bound (transcendentals + FMAs), tiny memory footprint.
// Split n into chunks for occupancy: grid = (batch/256, n/CHUNK) = (64,16),
// 1024 blocks -> ~4 waves/SIMD. Partial sums combined with fp32 atomicAdd
// into a memset-zeroed output. Chunk 0 adds the polynomial term.

#define CHUNK 256
#define BLK 256

__global__ __launch_bounds__(BLK) void tps_kernel(
    const float* __restrict__ u,     // (batch, 3)
    const float* __restrict__ cp,    // (n, 3)
    const float* __restrict__ w,     // (n, 3)
    const float* __restrict__ poly,  // (4, 3)
    float* __restrict__ out,         // (batch, 3)
    int batch, int n)
{
    __shared__ float s_cx[CHUNK], s_cy[CHUNK], s_cz[CHUNK];
    __shared__ float s_wx[CHUNK], s_wy[CHUNK], s_wz[CHUNK];

    const int tid = threadIdx.x;
    const int qi = blockIdx.x * BLK + tid;
    const int j0 = blockIdx.y * CHUNK;
    const int jn = min(CHUNK, n - j0);

    // Stage this chunk of control points + weights into LDS (SoA layout so
    // the unrolled inner loop can merge broadcast reads).
    if (tid < jn) {
        const int g = j0 + tid;
        s_cx[tid] = cp[g * 3 + 0];
        s_cy[tid] = cp[g * 3 + 1];
        s_cz[tid] = cp[g * 3 + 2];
        s_wx[tid] = w[g * 3 + 0];
        s_wy[tid] = w[g * 3 + 1];
        s_wz[tid] = w[g * 3 + 2];
    }
    __syncthreads();

    if (qi >= batch) return;

    const float ux = u[qi * 3 + 0];
    const float uy = u[qi * 3 + 1];
    const float uz = u[qi * 3 + 2];

    float ax = 0.f, ay = 0.f, az = 0.f;
    if (blockIdx.y == 0) {
        // polynomial term: poly[0] + ux*poly[1] + uy*poly[2] + uz*poly[3]
        ax = poly[0] + ux * poly[3] + uy * poly[6] + uz * poly[9];
        ay = poly[1] + ux * poly[4] + uy * poly[7] + uz * poly[10];
        az = poly[2] + ux * poly[5] + uy * poly[8] + uz * poly[11];
    }

    // r*ln(r) = sqrt(r2) * 0.5*ln(r2) = sqrt(r2) * (0.5*ln2) * log2(r2)
    const float C = 0.34657359027997264f;  // 0.5 * ln(2)

    if (jn == CHUNK) {
#pragma unroll 8
        for (int j = 0; j < CHUNK; ++j) {
            const float dx = ux - s_cx[j];
            const float dy = uy - s_cy[j];
            const float dz = uz - s_cz[j];
            float r2 = fmaxf(dx * dx + dy * dy + dz * dz, 1e-30f);
            const float k = __builtin_amdgcn_sqrtf(r2) *
                            (C * __builtin_amdgcn_logf(r2));
            ax = fmaf(k, s_wx[j], ax);
            ay = fmaf(k, s_wy[j], ay);
            az = fmaf(k, s_wz[j], az);
        }
    } else {
        for (int j = 0; j < jn; ++j) {
            const float dx = ux - s_cx[j];
            const float dy = uy - s_cy[j];
            const float dz = uz - s_cz[j];
            float r2 = fmaxf(dx * dx + dy * dy + dz * dz, 1e-30f);
            const float k = __builtin_amdgcn_sqrtf(r2) *
                            (C * __builtin_amdgcn_logf(r2));
            ax = fmaf(k, s_wx[j], ax);
            ay = fmaf(k, s_wy[j], ay);
            az = fmaf(k, s_wz[j], az);
        }
    }

    atomicAdd(&out[qi * 3 + 0], ax);
    atomicAdd(&out[qi * 3 + 1], ay);
    atomicAdd(&out[qi * 3 + 2], az);
}

extern "C" void kernel_launch(void* const* d_in, const int* in_sizes, int n_in,
                              void* d_out, int out_size, void* d_ws, size_t ws_size,
                              hipStream_t stream) {
    const float* u    = (const float*)d_in[0];  // (batch,3)
    const float* cp   = (const float*)d_in[1];  // (n,3)
    const float* w    = (const float*)d_in[2];  // (n,3)
    const float* poly = (const float*)d_in[3];  // (4,3)
    float* out = (float*)d_out;

    const int batch = in_sizes[0] / 3;
    const int n     = in_sizes[1] / 3;

    // Output is re-poisoned to 0xAA before every timed launch; zero it so the
    // atomic accumulation starts clean. hipMemsetAsync is graph-capturable.
    hipMemsetAsync(d_out, 0, (size_t)out_size * sizeof(float), stream);

    dim3 block(BLK);
    dim3 grid((batch + BLK - 1) / BLK, (n + CHUNK - 1) / CHUNK);
    tps_kernel<<<grid, block, 0, stream>>>(u, cp, w, poly, out, batch, n);
}

// Round 2
// 87.160 us; speedup vs baseline: 1.0642x; 1.0642x over previous
//
#include <hip/hip_runtime.h>

// ThinPlateSpline: out = K_query @ rbf_weights + P_query @ poly_coeffs
//   K_ij = r * ln(r),  r = ||u_i - c_j||  (d=3)
//   r*ln(r) = sqrt(r2) * 0.5*ln(2) * log2(r2); fold C=0.5*ln2 into staged w.
//
// R1 analysis: LDS-issue bound (6 ds_read_b32 per j-iter ~ 60us/CU of LDS pipe
// vs 17us VALU). Fix: Q=2 queries/lane amortizes LDS, and pack the chunk as
// float4 + float2 AoS so each j costs 2 LDS instrs (b128+b64) instead of 6.
// CHUNK=128, grid 32x32 = 1024 blocks -> 4 waves/SIMD.

#define CHUNK 128
#define BLK 256
#define QPT 2  // queries per thread

__global__ __launch_bounds__(BLK) void tps_kernel(
    const float* __restrict__ u,     // (batch, 3)
    const float* __restrict__ cp,    // (n, 3)
    const float* __restrict__ w,     // (n, 3)
    const float* __restrict__ poly,  // (4, 3)
    float* __restrict__ out,         // (batch, 3)
    int batch, int n)
{
    // Per control point j: A = (cx, cy, cz, C*wx), B = (C*wy, C*wz)
    __shared__ float4 s_a[CHUNK];
    __shared__ float2 s_b[CHUNK];

    const float C = 0.34657359027997264f;  // 0.5 * ln(2)

    const int tid = threadIdx.x;
    const int q0 = blockIdx.x * (BLK * QPT) + tid;   // query 0
    const int q1 = q0 + BLK;                          // query 1
    const int j0 = blockIdx.y * CHUNK;
    const int jn = min(CHUNK, n - j0);

    if (tid < jn) {
        const int g = j0 + tid;
        s_a[tid] = make_float4(cp[g * 3 + 0], cp[g * 3 + 1], cp[g * 3 + 2],
                               C * w[g * 3 + 0]);
        s_b[tid] = make_float2(C * w[g * 3 + 1], C * w[g * 3 + 2]);
    }
    __syncthreads();

    if (q0 >= batch) return;

    const float ux0 = u[q0 * 3 + 0], uy0 = u[q0 * 3 + 1], uz0 = u[q0 * 3 + 2];
    const float ux1 = u[q1 * 3 + 0], uy1 = u[q1 * 3 + 1], uz1 = u[q1 * 3 + 2];

    float ax0 = 0.f, ay0 = 0.f, az0 = 0.f;
    float ax1 = 0.f, ay1 = 0.f, az1 = 0.f;
    if (blockIdx.y == 0) {
        ax0 = poly[0] + ux0 * poly[3] + uy0 * poly[6] + uz0 * poly[9];
        ay0 = poly[1] + ux0 * poly[4] + uy0 * poly[7] + uz0 * poly[10];
        az0 = poly[2] + ux0 * poly[5] + uy0 * poly[8] + uz0 * poly[11];
        ax1 = poly[0] + ux1 * poly[3] + uy1 * poly[6] + uz1 * poly[9];
        ay1 = poly[1] + ux1 * poly[4] + uy1 * poly[7] + uz1 * poly[10];
        az1 = poly[2] + ux1 * poly[5] + uy1 * poly[8] + uz1 * poly[11];
    }

#pragma unroll 4
    for (int j = 0; j < jn; ++j) {
        const float4 A = s_a[j];
        const float2 B = s_b[j];

        const float dx0 = ux0 - A.x;
        const float dy0 = uy0 - A.y;
        const float dz0 = uz0 - A.z;
        float r20 = fmaxf(fmaf(dx0, dx0, fmaf(dy0, dy0, dz0 * dz0)), 1e-30f);
        const float k0 = __builtin_amdgcn_sqrtf(r20) * __builtin_amdgcn_logf(r20);
        ax0 = fmaf(k0, A.w, ax0);
        ay0 = fmaf(k0, B.x, ay0);
        az0 = fmaf(k0, B.y, az0);

        const float dx1 = ux1 - A.x;
        const float dy1 = uy1 - A.y;
        const float dz1 = uz1 - A.z;
        float r21 = fmaxf(fmaf(dx1, dx1, fmaf(dy1, dy1, dz1 * dz1)), 1e-30f);
        const float k1 = __builtin_amdgcn_sqrtf(r21) * __builtin_amdgcn_logf(r21);
        ax1 = fmaf(k1, A.w, ax1);
        ay1 = fmaf(k1, B.x, ay1);
        az1 = fmaf(k1, B.y, az1);
    }

    atomicAdd(&out[q0 * 3 + 0], ax0);
    atomicAdd(&out[q0 * 3 + 1], ay0);
    atomicAdd(&out[q0 * 3 + 2], az0);
    if (q1 < batch) {
        atomicAdd(&out[q1 * 3 + 0], ax1);
        atomicAdd(&out[q1 * 3 + 1], ay1);
        atomicAdd(&out[q1 * 3 + 2], az1);
    }
}

extern "C" void kernel_launch(void* const* d_in, const int* in_sizes, int n_in,
                              void* d_out, int out_size, void* d_ws, size_t ws_size,
                              hipStream_t stream) {
    const float* u    = (const float*)d_in[0];  // (batch,3)
    const float* cp   = (const float*)d_in[1];  // (n,3)
    const float* w    = (const float*)d_in[2];  // (n,3)
    const float* poly = (const float*)d_in[3];  // (4,3)
    float* out = (float*)d_out;

    const int batch = in_sizes[0] / 3;
    const int n     = in_sizes[1] / 3;

    // Zero the output so the atomic accumulation starts clean (d_out is
    // poisoned to 0xAA before every timed launch).
    hipMemsetAsync(d_out, 0, (size_t)out_size * sizeof(float), stream);

    dim3 block(BLK);
    dim3 grid((batch + BLK * QPT - 1) / (BLK * QPT), (n + CHUNK - 1) / CHUNK);
    tps_kernel<<<grid, block, 0, stream>>>(u, cp, w, poly, out, batch, n);
}